// Round 2
// baseline (322.334 us; speedup 1.0000x reference)
//
#include <hip/hip_runtime.h>

// CostVolume via bf16 MFMA Gram band: cost[b,d,h,w] = (1/64)·G[w][w-d],
// G = L^T·R per (b,h), banded (0 <= d < 48). B=4 C=64 H=256 W=512 D=48.
//
// Round-5 restructure (latency-bound per r1 counters: all pipes <25% busy,
// occupancy 35.7%):
//  * TW 256 -> 128: LDS 35840 -> 19456 B, launch_bounds(256,6) -> 6 blocks
//    (24 waves) per CU, 6 independent barrier groups to keep HBM loads
//    outstanding continuously (was 4 lockstepped blocks = 16 waves).
//  * staging task map (c from tid&7, w-quad from tid>>3) + row-parity
//    swizzle row' = w ^ ((w>>2)&1): ds_write_b64 lanes now spread across
//    all 32 banks (was 16 lanes on one 2-bank pair = 4x conflict, 22% of
//    CU cycles per r1 SQ_LDS_BANK_CONFLICT). Fragment b128 reads keep the
//    8-cycle optimum under the same swizzle (XOR bit = (n16>>2)&1).
//  * epilogue unchanged in structure: scratch scatter + full-128B-line
//    nontemporal stores (ST=129 keeps the <=2-way scatter property).

#define BB 4
#define CC 64
#define HH 256
#define WW 512
#define DD 48
#define TW 128
#define CK 32          // channel chunk (= MFMA K)
#define RWIN 176       // right window cols: w0-48 .. w0+127
#define WR 32          // shorts per LDS row (64 B)
#define ST 129         // epilogue scratch row stride (fp32)
#define NT 256

typedef short bf16x8 __attribute__((ext_vector_type(8)));
typedef float f32x4  __attribute__((ext_vector_type(4)));

// fp32 -> bf16 round-to-nearest-even, packed pair (lo in bits 15:0)
__device__ __forceinline__ unsigned int f2bf2(float lo, float hi) {
  unsigned int a = __float_as_uint(lo);
  unsigned int b = __float_as_uint(hi);
  a = (a + 0x7fffu + ((a >> 16) & 1u)) >> 16;
  b = (b + 0x7fffu + ((b >> 16) & 1u)) & 0xffff0000u;
  return a | b;
}

// physical LDS row: mix w bit2 into bit0 so one staging write instruction
// (w = 4*lanehi + j, j fixed) spans both 16-bank halves
__device__ __forceinline__ int rowswz(int w) { return w ^ ((w >> 2) & 1); }

__global__ __launch_bounds__(NT, 6)
void cost_volume_mfma(const float* __restrict__ left,
                      const float* __restrict__ right,
                      float* __restrict__ out) {
  // (128+176) rows x 64 B = 19456 B; epilogue scratch (24*129*4 = 12384 B)
  // aliases the same region.
  __shared__ __align__(16) char smem[(TW + RWIN) * WR * 2];
  unsigned short* sL = reinterpret_cast<unsigned short*>(smem);   // [w][c]
  unsigned short* sR = sL + TW * WR;                              // [w'][c]
  float*          scr = reinterpret_cast<float*>(smem);

  const int w0   = blockIdx.x * TW;   // 0,128,256,384
  const int h    = blockIdx.y;
  const int b    = blockIdx.z;
  const int tid  = threadIdx.x;
  const int lane = tid & 63;
  const int wv   = tid >> 6;          // wave 0..3
  const int n16  = lane & 15;
  const int q    = lane >> 4;
  const int xb   = (n16 >> 2) & 1;    // read-side row-swizzle bit

  const size_t HWs   = (size_t)HH * WW;
  const size_t bbase = ((size_t)b * CC) * HWs + (size_t)h * WW;

  // staging task coords: c-quad varies across low lane bits (bank spread),
  // w-quad across high bits (keeps each c-row's 8 lanes on one 128B line)
  const int scq4 = 4 * (tid & 7);     // 0..28
  const int swq4 = 4 * (tid >> 3);    // 0..124

  f32x4 acc[2][4];
  #pragma unroll
  for (int i = 0; i < 2; ++i)
    #pragma unroll
    for (int t = 0; t < 4; ++t)
      acc[i][t] = (f32x4){0.f, 0.f, 0.f, 0.f};

  for (int c0 = 0; c0 < CC; c0 += CK) {
    // ---- stage left tile: 32 w-quads x 8 c-quads = 256 tasks (1/thread)
    {
      f32x4 v[4];
      #pragma unroll
      for (int r = 0; r < 4; ++r)
        v[r] = *reinterpret_cast<const f32x4*>(
            left + bbase + (size_t)(c0 + scq4 + r) * HWs + w0 + swq4);
      #pragma unroll
      for (int j = 0; j < 4; ++j) {
        uint2 pk;
        pk.x = f2bf2(v[0][j], v[1][j]);
        pk.y = f2bf2(v[2][j], v[3][j]);
        *reinterpret_cast<uint2*>(&sL[rowswz(swq4 + j) * WR + scq4]) = pk;
      }
    }
    // ---- stage right window: 44 w-quads x 8 c-quads = 352 tasks
    // task 0: all 256 threads (w'4 = swq4); task 1: 96 threads (w'4+128).
    #pragma unroll
    for (int rep = 0; rep < 2; ++rep) {
      const int wr4 = swq4 + 128 * rep;
      if (rep == 0 || tid < 96) {
        const int g4 = w0 - 48 + wr4;   // global col of this quad
        f32x4 v[4];
        if (g4 >= 0) {
          #pragma unroll
          for (int r = 0; r < 4; ++r)
            v[r] = *reinterpret_cast<const f32x4*>(
                right + bbase + (size_t)(c0 + scq4 + r) * HWs + g4);
        } else {
          #pragma unroll
          for (int r = 0; r < 4; ++r) v[r] = (f32x4){0.f, 0.f, 0.f, 0.f};
        }
        #pragma unroll
        for (int j = 0; j < 4; ++j) {
          uint2 pk;
          pk.x = f2bf2(v[0][j], v[1][j]);
          pk.y = f2bf2(v[2][j], v[3][j]);
          *reinterpret_cast<uint2*>(&sR[rowswz(wr4 + j) * WR + scq4]) = pk;
        }
      }
    }
    __syncthreads();

    // ---- compute: A[m][k] = L[k][u0+m], B[k][n] = R[k][u0+16t+n-48].
    // One ds_read_b128 per fragment (8 consecutive c at one w-row).
    #pragma unroll
    for (int i = 0; i < 2; ++i) {
      const int u0 = 16 * (wv + 4 * i);
      const bf16x8 A = *reinterpret_cast<const bf16x8*>(
          &sL[((u0 + n16) ^ xb) * WR + 8 * q]);
      #pragma unroll
      for (int t = 0; t < 4; ++t) {
        const int rB = u0 + 16 * t + n16;      // sR row = v_global - w0 + 48
        const bf16x8 Bv = *reinterpret_cast<const bf16x8*>(
            &sR[(rB ^ xb) * WR + 8 * q]);
        acc[i][t] =
            __builtin_amdgcn_mfma_f32_16x16x32_bf16(A, Bv, acc[i][t], 0, 0, 0);
      }
    }
    __syncthreads();  // next chunk (or epilogue scratch) reuses LDS
  }

  // ---- epilogue: block-wide scratch, 2 halves of 24 d-rows each
  const float scale = 1.0f / 64.0f;
  #pragma unroll 1
  for (int half = 0; half < 2; ++half) {
    const int dbase = 24 * half;
    if (half) __syncthreads();   // half-0 E2 reads done before overwrite
    // E1: scatter acc -> scr[d - dbase][u0 + m]  (<=2-way LDS aliasing)
    #pragma unroll
    for (int i = 0; i < 2; ++i) {
      const int u0 = 16 * (wv + 4 * i);
      #pragma unroll
      for (int t = 0; t < 4; ++t)
        #pragma unroll
        for (int r = 0; r < 4; ++r) {
          const int m = 4 * q + r;
          const int d = m - n16 + 48 - 16 * t;
          const unsigned int dr = (unsigned int)(d - dbase);
          if (dr < 24u) scr[dr * ST + u0 + m] = acc[i][t][r] * scale;
        }
    }
    __syncthreads();
    // E2: cooperative full-line stores: 24 rows x 32 float4 (each 512B row
    // = 4 full 128B lines, written exactly once), non-temporal.
    const size_t obase = (((size_t)b * DD + dbase) * HH + h) * WW + w0;
    #pragma unroll
    for (int s3 = 0; s3 < 3; ++s3) {
      const int s  = tid + s3 * NT;
      const int dr = s >> 5;
      const int p  = s & 31;
      const f32x4 v = *reinterpret_cast<const f32x4*>(&scr[dr * ST + 4 * p]);
      __builtin_nontemporal_store(
          v, reinterpret_cast<f32x4*>(out + obase + (size_t)dr * HWs + 4 * p));
    }
  }
}

extern "C" void kernel_launch(void* const* d_in, const int* in_sizes, int n_in,
                              void* d_out, int out_size, void* d_ws, size_t ws_size,
                              hipStream_t stream) {
  const float* left  = (const float*)d_in[0];
  const float* right = (const float*)d_in[1];
  float* out = (float*)d_out;

  dim3 grid(WW / TW, HH, BB);   // 4 x 256 x 4 = 4096 blocks
  dim3 block(NT);
  cost_volume_mfma<<<grid, block, 0, stream>>>(left, right, out);
}